// Round 1
// baseline (16.681 us; speedup 1.0000x reference)
//
#include <hip/hip_runtime.h>

namespace {
constexpr int IC = 32;
constexpr int OC = 32;
constexpr int HW = 1024;            // 32*32 spatial
constexpr int H2 = 16, W2 = 16;     // pooled dims
}

// Block = 512 threads (8 waves), tile 8n x 8o x one strip (2 h-rows x 32 w = 64 pos).
// Grid = 512 = (8 n-tiles x 4 o-tiles) x 16 strips; bid = tile*16 + s so
// XCD(bid%8) = s%8: both strips of an XCD need only 1.57 MB -> L2-resident re-reads.
// LDS 66 KB -> 2 blocks/CU: two independent barrier domains overlap phases.
// LDS layout is ki-contiguous with XOR swizzle so all compute reads are ds_read_b128:
//   float index of (c, pos, g, kk) = ((c*64+pos)*4 + (g ^ ((pos>>1)&3)))*4 + kk
//   bank-quad = 4*(pos&1) + (g^((pos>>1)&3)) -> 8 quads x 8 lanes = conflict-free.
__global__ __launch_bounds__(512, 4) void sumprod_fused(
    const float* __restrict__ x, const float* __restrict__ logits,
    float* __restrict__ out)
{
    __shared__ __align__(16) float exl[8 * 64 * 16];  // exp(x):      8n x 64pos x 16ki, 32 KB
    __shared__ __align__(16) float ewl[8 * 64 * 16];  // exp(logits): 8o x 64pos x 16ki, 32 KB
    __shared__ float wsl[8 * 64];                     // softmax denominators [o8][pos64]

    const int tid  = threadIdx.x;
    const int lane = tid & 63;
    const int w    = tid >> 6;          // wave id = staging row (n and o)
    const int bid  = blockIdx.x;
    const int s    = bid & 15;          // strip (== h2)
    const int tt   = bid >> 4;          // 0..31
    const int n0   = (tt & 7) * 8;
    const int o0   = (tt >> 3) * 8;

    const int sw   = (lane >> 1) & 3;   // per-lane swizzle bits
    const int gpos = s * 64 + lane;     // element offset within one 32x32 plane

    const float* gx = x      + (n0 + w) * IC * HW + gpos;
    const float* gw = logits + (o0 + w) * IC * HW + gpos;
    float* exrow = &exl[(w * 64 + lane) << 4];
    float* ewrow = &ewl[(w * 64 + lane) << 4];

    float dsum = 0.f;   // softmax denominator for (o0+w, pos) accumulated in-register

    // ---- stage chunk 0 (i = 0..15): coalesced dword loads, b128 swizzled writes
    #pragma unroll
    for (int ig = 0; ig < 4; ++ig) {
        const float v0 = gx[(4 * ig + 0) * HW], v1 = gx[(4 * ig + 1) * HW];
        const float v2 = gx[(4 * ig + 2) * HW], v3 = gx[(4 * ig + 3) * HW];
        float4 e;
        e.x = __expf(v0); e.y = __expf(v1); e.z = __expf(v2); e.w = __expf(v3);
        *reinterpret_cast<float4*>(exrow + ((ig ^ sw) << 2)) = e;
    }
    #pragma unroll
    for (int ig = 0; ig < 4; ++ig) {
        const float v0 = gw[(4 * ig + 0) * HW], v1 = gw[(4 * ig + 1) * HW];
        const float v2 = gw[(4 * ig + 2) * HW], v3 = gw[(4 * ig + 3) * HW];
        float4 e;
        e.x = __expf(v0); e.y = __expf(v1); e.z = __expf(v2); e.w = __expf(v3);
        dsum += (e.x + e.y) + (e.z + e.w);
        *reinterpret_cast<float4*>(ewrow + ((ig ^ sw) << 2)) = e;
    }
    __syncthreads();

    // ---- prefetch chunk 1 (i = 16..31) into registers; completes under compute-0
    float vx[16], vw[16];
    #pragma unroll
    for (int i = 0; i < 16; ++i) vx[i] = gx[(16 + i) * HW];
    #pragma unroll
    for (int i = 0; i < 16; ++i) vw[i] = gw[(16 + i) * HW];

    // ---- compute tile: wave = 4n x 2o, lane = position
    const int nw = (w & 1) * 4;
    const int ow = (w >> 1) * 2;
    const float* a0p = &exl[((nw + 0) * 64 + lane) << 4];
    const float* a1p = &exl[((nw + 1) * 64 + lane) << 4];
    const float* a2p = &exl[((nw + 2) * 64 + lane) << 4];
    const float* a3p = &exl[((nw + 3) * 64 + lane) << 4];
    const float* b0p = &ewl[((ow + 0) * 64 + lane) << 4];
    const float* b1p = &ewl[((ow + 1) * 64 + lane) << 4];

    float acc[4][2] = {};

#define FMA4(ACC, A, B)                                                   \
    ACC = fmaf((A).x, (B).x, ACC); ACC = fmaf((A).y, (B).y, ACC);         \
    ACC = fmaf((A).z, (B).z, ACC); ACC = fmaf((A).w, (B).w, ACC);

#define COMPUTE_CHUNK()                                                   \
    _Pragma("unroll")                                                     \
    for (int g = 0; g < 4; ++g) {                                         \
        const int sl = ((g ^ sw) << 2);                                   \
        const float4 a0 = *reinterpret_cast<const float4*>(a0p + sl);     \
        const float4 a1 = *reinterpret_cast<const float4*>(a1p + sl);     \
        const float4 a2 = *reinterpret_cast<const float4*>(a2p + sl);     \
        const float4 a3 = *reinterpret_cast<const float4*>(a3p + sl);     \
        const float4 b0 = *reinterpret_cast<const float4*>(b0p + sl);     \
        const float4 b1 = *reinterpret_cast<const float4*>(b1p + sl);     \
        FMA4(acc[0][0], a0, b0); FMA4(acc[0][1], a0, b1);                 \
        FMA4(acc[1][0], a1, b0); FMA4(acc[1][1], a1, b1);                 \
        FMA4(acc[2][0], a2, b0); FMA4(acc[2][1], a2, b1);                 \
        FMA4(acc[3][0], a3, b0); FMA4(acc[3][1], a3, b1);                 \
    }

    COMPUTE_CHUNK();          // i = 0..15
    __syncthreads();          // all reads of chunk-0 buffers complete

    // ---- write chunk 1 (exp applied now; loads landed under compute-0)
    #pragma unroll
    for (int ig = 0; ig < 4; ++ig) {
        float4 e;
        e.x = __expf(vx[4 * ig + 0]); e.y = __expf(vx[4 * ig + 1]);
        e.z = __expf(vx[4 * ig + 2]); e.w = __expf(vx[4 * ig + 3]);
        *reinterpret_cast<float4*>(exrow + ((ig ^ sw) << 2)) = e;
    }
    #pragma unroll
    for (int ig = 0; ig < 4; ++ig) {
        float4 e;
        e.x = __expf(vw[4 * ig + 0]); e.y = __expf(vw[4 * ig + 1]);
        e.z = __expf(vw[4 * ig + 2]); e.w = __expf(vw[4 * ig + 3]);
        dsum += (e.x + e.y) + (e.z + e.w);
        *reinterpret_cast<float4*>(ewrow + ((ig ^ sw) << 2)) = e;
    }
    wsl[w * 64 + lane] = dsum;   // full 32-i denominator, ready before next barrier
    __syncthreads();

    COMPUTE_CHUNK();          // i = 16..31

#undef COMPUTE_CHUNK
#undef FMA4

    // ---- epilogue: log, subtract pooled log-denominator, 2x2 pool via shuffles
    const float lw0 = __logf(wsl[(ow + 0) * 64 + lane]);
    const float lw1 = __logf(wsl[(ow + 1) * 64 + lane]);

    #pragma unroll
    for (int k = 0; k < 4; ++k) {
        #pragma unroll
        for (int j = 0; j < 2; ++j) {
            float v = __logf(acc[k][j]) - (j ? lw1 : lw0);
            v += __shfl_xor(v, 1);    // pool over w-pair
            v += __shfl_xor(v, 32);   // pool over h-pair
            if ((lane & 33) == 0) {   // even lane, h_lo == 0
                const int w2 = (lane >> 1) & 15;
                out[((n0 + nw + k) * OC + (o0 + ow + j)) * (H2 * W2) + s * W2 + w2] = v;
            }
        }
    }
}

extern "C" void kernel_launch(void* const* d_in, const int* in_sizes, int n_in,
                              void* d_out, int out_size, void* d_ws, size_t ws_size,
                              hipStream_t stream) {
    const float* x      = (const float*)d_in[0];
    const float* logits = (const float*)d_in[1];
    float* out = (float*)d_out;
    hipLaunchKernelGGL(sumprod_fused, dim3(512), dim3(512), 0, stream,
                       x, logits, out);
}

// Round 3
// 12.680 us; speedup vs baseline: 1.3156x; 1.3156x over previous
//
#include <hip/hip_runtime.h>

namespace {
constexpr int IC = 32;
constexpr int OC = 32;
constexpr int HW = 1024;            // 32*32 spatial
constexpr int H2 = 16, W2 = 16;     // pooled dims

typedef _Float16 half2v __attribute__((ext_vector_type(2)));

#if defined(__has_builtin)
#if __has_builtin(__builtin_amdgcn_fdot2)
#define HAVE_FDOT2 1
#endif
#endif

__device__ __forceinline__ float dot2acc(half2v a, half2v b, float c) {
#ifdef HAVE_FDOT2
    return __builtin_amdgcn_fdot2(a, b, c, false);   // v_dot2_f32_f16
#else
    return fmaf((float)a.x, (float)b.x, fmaf((float)a.y, (float)b.y, c));
#endif
}

__device__ __forceinline__ half2v u2h(unsigned int u) {
    union { unsigned int u; half2v h; } x; x.u = u; return x.h;
}

__device__ __forceinline__ half2v pk2(float a, float b) {
    union { decltype(__builtin_amdgcn_cvt_pkrtz(0.f, 0.f)) p; half2v h; } x;
    x.p = __builtin_amdgcn_cvt_pkrtz(a, b);   // v_cvt_pkrtz_f16_f32
    return x.h;
}
}

// Block = 512 threads (8 waves), tile 8n x 8o x one strip (2 h-rows x 32 w = 64 pos).
// Grid 512 = 32 tiles x 16 strips; bid = tt*16 + s -> XCD(bid%8)=s%8 keeps a strip's
// x/logits re-reads on one XCD's L2.
// LDS 66 KB -> 2 blocks/CU (two barrier domains overlap stage/compute phases).
// exp values stored as packed f16 pairs (i-pair per 4B); inner product via v_dot2_f32_f16.
// Swizzle: value (row, p, ip) lives at h2-index (row*64+p)*16 + ((ip>>2)^sw(p))*4 + (ip&3),
// sw(p) = ((p>>1)^(p>>3))&3. Reads: ds_read_b128 per (row, gg) conflict-free
// (8 distinct bank-quads per 8-lane phase group); staged writes ~4-way (cheap).
// exl holds all 32 i: chunk-1 writes (slots g=2,3) are disjoint from chunk-0 reads
// (g=0,1) -> only 2 barriers total.
__global__ __launch_bounds__(512, 4) void sumprod_fused(
    const float* __restrict__ x, const float* __restrict__ logits,
    float* __restrict__ out)
{
    __shared__ half2v exl[8 * 64 * 16];   // exp(x)   [n8][p64][16 ip slots] 32 KB
    __shared__ half2v ewl[8 * 64 * 16];   // exp(lgt) [o8][p64][16 ip slots] 32 KB
    __shared__ float  wsl[8 * 64];        // softmax denominators [o8][p64]

    const int tid  = threadIdx.x;
    const int lane = tid & 63;
    const int w    = tid >> 6;          // wave id = staging row (n and o)
    const int bid  = blockIdx.x;
    const int s    = bid & 15;          // strip (== h2)
    const int tt   = bid >> 4;          // 0..31
    const int n0   = (tt & 7) * 8;
    const int o0   = (tt >> 3) * 8;

    const int kk    = (tid >> 4) & 3;   // element slot within b128 group
    const int p4    = tid & 15;         // float4 slot in strip
    const int spoff = (2 * s + (p4 >> 3)) * 32 + (p4 & 7) * 4;

    const float* gx = x      + (size_t)(n0 + w) * IC * HW + spoff;
    const float* gw = logits + (size_t)(o0 + w) * IC * HW + spoff;

    // exp + pack f16 pair + swizzled LDS write of one float4-pair task
    auto stage = [&](half2v* buf, const float4& va, const float4& vb, int ip) {
        const float* pa = reinterpret_cast<const float*>(&va);
        const float* pb = reinterpret_cast<const float*>(&vb);
        #pragma unroll
        for (int j = 0; j < 4; ++j) {
            const int p    = (p4 >> 3) * 32 + (p4 & 7) * 4 + j;
            const int slot = (ip >> 2) ^ (((p >> 1) ^ (p >> 3)) & 3);
            buf[(w * 64 + p) * 16 + slot * 4 + (ip & 3)] =
                pk2(__expf(pa[j]), __expf(pb[j]));
        }
    };

    // ---- stage exp(logits) full (ip 0..15) + exp(x) chunk 0 (ip 0..7)
    #pragma unroll
    for (int g = 0; g < 4; ++g) {
        const int ip = g * 4 + kk;
        const float4 va = *reinterpret_cast<const float4*>(&gw[(2 * ip) * HW]);
        const float4 vb = *reinterpret_cast<const float4*>(&gw[(2 * ip + 1) * HW]);
        stage(ewl, va, vb, ip);
    }
    #pragma unroll
    for (int g = 0; g < 2; ++g) {
        const int ip = g * 4 + kk;
        const float4 va = *reinterpret_cast<const float4*>(&gx[(2 * ip) * HW]);
        const float4 vb = *reinterpret_cast<const float4*>(&gx[(2 * ip + 1) * HW]);
        stage(exl, va, vb, ip);
    }
    __syncthreads();

    // ---- prefetch x chunk 1 (ip 8..15) into registers; lands under compute-0
    float4 pva[2], pvb[2];
    #pragma unroll
    for (int g = 0; g < 2; ++g) {
        const int ip = (g + 2) * 4 + kk;
        pva[g] = *reinterpret_cast<const float4*>(&gx[(2 * ip) * HW]);
        pvb[g] = *reinterpret_cast<const float4*>(&gx[(2 * ip + 1) * HW]);
    }

    const int swl = ((lane >> 1) ^ (lane >> 3)) & 3;

    // ---- softmax denominators: thread (o=w, p=lane), conflict-free b128 reads
    {
        float ds = 0.f;
        const half2v one2 = {(_Float16)1.f, (_Float16)1.f};
        #pragma unroll
        for (int gg = 0; gg < 4; ++gg) {
            const uint4 B = *reinterpret_cast<const uint4*>(
                &ewl[(w * 64 + lane) * 16 + ((gg ^ swl) * 4)]);
            ds = dot2acc(u2h(B.x), one2, ds);
            ds = dot2acc(u2h(B.y), one2, ds);
            ds = dot2acc(u2h(B.z), one2, ds);
            ds = dot2acc(u2h(B.w), one2, ds);
        }
        wsl[w * 64 + lane] = ds;
    }

    // ---- compute: wave tile 4n x 2o, lane = position
    const int nw = (w & 1) * 4;
    const int ow = (w >> 1) * 2;
    float acc[4][2] = {};

#define D2(AA, BB, K, J) acc[K][J] = dot2acc(u2h(AA), u2h(BB), acc[K][J])
#define QUAD(A_, K_)                                                          \
    D2(A_.x, B0.x, K_, 0); D2(A_.y, B0.y, K_, 0);                             \
    D2(A_.z, B0.z, K_, 0); D2(A_.w, B0.w, K_, 0);                             \
    D2(A_.x, B1.x, K_, 1); D2(A_.y, B1.y, K_, 1);                             \
    D2(A_.z, B1.z, K_, 1); D2(A_.w, B1.w, K_, 1)
#define COMPUTE_GG(GG) {                                                      \
    const int off = ((GG) ^ swl) * 4;                                         \
    const uint4 A0 = *reinterpret_cast<const uint4*>(&exl[((nw + 0) * 64 + lane) * 16 + off]); \
    const uint4 A1 = *reinterpret_cast<const uint4*>(&exl[((nw + 1) * 64 + lane) * 16 + off]); \
    const uint4 A2 = *reinterpret_cast<const uint4*>(&exl[((nw + 2) * 64 + lane) * 16 + off]); \
    const uint4 A3 = *reinterpret_cast<const uint4*>(&exl[((nw + 3) * 64 + lane) * 16 + off]); \
    const uint4 B0 = *reinterpret_cast<const uint4*>(&ewl[((ow + 0) * 64 + lane) * 16 + off]); \
    const uint4 B1 = *reinterpret_cast<const uint4*>(&ewl[((ow + 1) * 64 + lane) * 16 + off]); \
    QUAD(A0, 0); QUAD(A1, 1); QUAD(A2, 2); QUAD(A3, 3); }

    COMPUTE_GG(0);
    COMPUTE_GG(1);

    // ---- write x chunk 1 (slots g=2,3; disjoint from chunk-0 reads -> no barrier
    // needed before, only after). exp applied now; loads landed under compute-0.
    #pragma unroll
    for (int g = 0; g < 2; ++g) {
        const int ip = (g + 2) * 4 + kk;
        stage(exl, pva[g], pvb[g], ip);
    }
    __syncthreads();

    COMPUTE_GG(2);
    COMPUTE_GG(3);

#undef COMPUTE_GG
#undef QUAD
#undef D2

    // ---- epilogue: log, subtract pooled log-denominator, 2x2 pool via shuffles
    const float lw0 = __logf(wsl[(ow + 0) * 64 + lane]);
    const float lw1 = __logf(wsl[(ow + 1) * 64 + lane]);

    #pragma unroll
    for (int k = 0; k < 4; ++k) {
        #pragma unroll
        for (int j = 0; j < 2; ++j) {
            float v = __logf(acc[k][j]) - (j ? lw1 : lw0);
            v += __shfl_xor(v, 1);    // pool over w-pair
            v += __shfl_xor(v, 32);   // pool over h-pair
            if ((lane & 33) == 0) {   // even lane, h_lo == 0
                const int w2 = (lane >> 1) & 15;
                out[((n0 + nw + k) * OC + (o0 + ow + j)) * (H2 * W2) + s * W2 + w2] = v;
            }
        }
    }
}

extern "C" void kernel_launch(void* const* d_in, const int* in_sizes, int n_in,
                              void* d_out, int out_size, void* d_ws, size_t ws_size,
                              hipStream_t stream) {
    const float* x      = (const float*)d_in[0];
    const float* logits = (const float*)d_in[1];
    float* out = (float*)d_out;
    hipLaunchKernelGGL(sumprod_fused, dim3(512), dim3(512), 0, stream,
                       x, logits, out);
}